// Round 11
// baseline (770.077 us; speedup 1.0000x reference)
//
#include <hip/hip_runtime.h>
#include <hip/hip_bf16.h>
#include <math.h>
#include <stdint.h>
#include <stdio.h>

#define DIMD 512
#define FFD  2048
#define NEXP 8
#define NTOK 32768          // 8*4096 tokens
#define BM   128            // m-tile granularity of the tile map
#define MAXT 520            // max m-tiles: 65536/128 + 8
#define PADMAX (MAXT * BM)  // 66560 padded slots
#define NCHUNK 4
#define TPC    130          // tiles per chunk (MAXT/NCHUNK)

typedef unsigned short u16;
typedef __attribute__((ext_vector_type(8))) short bf16x8;
typedef __attribute__((ext_vector_type(4))) float f32x4;
typedef __attribute__((ext_vector_type(4))) unsigned short u16x4;

// meta layout (ints): [0..7] counts, [8..15] fills, [16..23] seg starts,
// [24] numTiles, [32..32+MAXT) tileExpert, [560..560+MAXT) tileRow
#define META_TE   32
#define META_TR   560

__device__ __forceinline__ void async16(const void* g, void* l) {
  __builtin_amdgcn_global_load_lds(
      (const __attribute__((address_space(1))) unsigned int*)g,
      (__attribute__((address_space(3))) unsigned int*)l, 16, 0, 0);
}

__device__ __forceinline__ float bf2f(short s) {
  unsigned int u = ((unsigned int)(u16)s) << 16;
  return __uint_as_float(u);
}
__device__ __forceinline__ u16 f2bf(float f) {
  __hip_bfloat16 h = __float2bfloat16(f);
  return *(u16*)&h;
}

// counted vmcnt wait (compile-time literal per T4 discipline)
template <int N>
__device__ __forceinline__ void wait_vm() {
  if constexpr (N == 0)      asm volatile("s_waitcnt vmcnt(0)" ::: "memory");
  else if constexpr (N == 3) asm volatile("s_waitcnt vmcnt(3)" ::: "memory");
  else if constexpr (N == 4) asm volatile("s_waitcnt vmcnt(4)" ::: "memory");
  else if constexpr (N == 6) asm volatile("s_waitcnt vmcnt(6)" ::: "memory");
  else                       asm volatile("s_waitcnt vmcnt(8)" ::: "memory");
}

// ---------- 1. zero the atomic counters ----------
__global__ void init_kernel(int* __restrict__ meta) {
  if (threadIdx.x < 16) meta[threadIdx.x] = 0;
}

// ---------- 2. router + x->bf16: 4 waves/block, 1 token/wave, coalesced.
// fp64 logits, deterministic butterfly reduce, top-2 softmax gates.
__global__ __launch_bounds__(256) void router_kernel(
    const float* __restrict__ x, const float* __restrict__ Wr,
    u16* __restrict__ xb, int* __restrict__ eidx, float* __restrict__ gat) {
  __shared__ float wrs[NEXP * DIMD];  // 16 KB
  int tid = threadIdx.x, l = tid & 63, w = tid >> 6;
  for (int i = tid * 4; i < NEXP * DIMD; i += 1024)
    *(float4*)&wrs[i] = *(const float4*)&Wr[i];
  __syncthreads();

  int t = blockIdx.x * 4 + w;
  const float* xr = x + (size_t)t * DIMD + l * 8;
  float4 a = *(const float4*)xr;
  float4 b = *(const float4*)(xr + 4);

  // fused x -> bf16 (coalesced 16B/lane)
  bf16x8 xo;
  xo[0] = (short)f2bf(a.x); xo[1] = (short)f2bf(a.y);
  xo[2] = (short)f2bf(a.z); xo[3] = (short)f2bf(a.w);
  xo[4] = (short)f2bf(b.x); xo[5] = (short)f2bf(b.y);
  xo[6] = (short)f2bf(b.z); xo[7] = (short)f2bf(b.w);
  *(bf16x8*)&xb[(size_t)t * DIMD + l * 8] = xo;

  double p[NEXP];
#pragma unroll
  for (int e = 0; e < NEXP; ++e) {
    const float* wr = &wrs[e * DIMD + l * 8];
    p[e] = (double)a.x * wr[0] + (double)a.y * wr[1] +
           (double)a.z * wr[2] + (double)a.w * wr[3] +
           (double)b.x * wr[4] + (double)b.y * wr[5] +
           (double)b.z * wr[6] + (double)b.w * wr[7];
  }
#pragma unroll
  for (int off = 1; off < 64; off <<= 1) {
#pragma unroll
    for (int e = 0; e < NEXP; ++e) p[e] += __shfl_xor(p[e], off);
  }
  if (l == 0) {
    int b0 = 0; double v0 = p[0];
#pragma unroll
    for (int e = 1; e < NEXP; ++e) if (p[e] > v0) { v0 = p[e]; b0 = e; }
    int b1 = -1; double v1 = -1e300;
#pragma unroll
    for (int e = 0; e < NEXP; ++e) {
      if (e == b0) continue;
      if (b1 < 0 || p[e] > v1) { v1 = p[e]; b1 = e; }
    }
    float e1 = expf((float)(v1 - v0));
    float inv = 1.0f / (1.0f + e1);
    eidx[t * 2] = b0; eidx[t * 2 + 1] = b1;
    gat[t * 2] = inv; gat[t * 2 + 1] = e1 * inv;
  }
}

// ---------- 2b. expert histogram with LDS pre-aggregation ----------
__global__ __launch_bounds__(256) void count_kernel(const int* __restrict__ eidx,
                                                    int* __restrict__ meta) {
  __shared__ int h[NEXP];
  if (threadIdx.x < NEXP) h[threadIdx.x] = 0;
  __syncthreads();
  int i = blockIdx.x * 256 + threadIdx.x;  // over NTOK*2
  atomicAdd(&h[eidx[i]], 1);
  __syncthreads();
  if (threadIdx.x < NEXP) atomicAdd(&meta[threadIdx.x], h[threadIdx.x]);
}

// ---------- 3. scan: segment starts (128-aligned), tile map, pad perm ----------
__global__ void scan_kernel(int* __restrict__ meta, int* __restrict__ perm) {
  __shared__ int s_start[NEXP], s_cnt[NEXP], s_tiles[NEXP];
  __shared__ int s_tbase[NEXP];
  if (threadIdx.x == 0) {
    int cum = 0, tb = 0;
    for (int e = 0; e < NEXP; ++e) {
      int c = meta[e];
      s_cnt[e] = c; s_start[e] = cum; s_tbase[e] = tb;
      meta[16 + e] = cum;
      int nt = (c + BM - 1) / BM;
      s_tiles[e] = nt;
      tb += nt;
      cum += nt * BM;
    }
    meta[24] = tb;
  }
  __syncthreads();
  for (int e = 0; e < NEXP; ++e) {
    for (int i = threadIdx.x; i < s_tiles[e]; i += blockDim.x) {
      meta[META_TE + s_tbase[e] + i] = e;
      meta[META_TR + s_tbase[e] + i] = s_start[e] + i * BM;
    }
    int npad = s_tiles[e] * BM - s_cnt[e];
    for (int i = threadIdx.x; i < npad; i += blockDim.x)
      perm[s_start[e] + s_cnt[e] + i] = 0;   // pad slots point at token 0
  }
}

// ---------- 4. scatter: slot assignment, block-aggregated atomics ----------
__global__ __launch_bounds__(256) void scatter_kernel(
    const int* __restrict__ eidx, int* __restrict__ meta,
    int* __restrict__ perm, int* __restrict__ slot) {
  __shared__ int wcnt[4][NEXP], wpre[4][NEXP], base[NEXP];
  int tid = threadIdx.x, l = tid & 63, w = tid >> 6;
  int i = blockIdx.x * 256 + tid;  // over NTOK*2
  int e = eidx[i];
  unsigned long long lmask = (l == 63) ? ~0ull >> 1 : ((1ull << l) - 1);
  int rank = 0;
#pragma unroll
  for (int ee = 0; ee < NEXP; ++ee) {
    unsigned long long m = __ballot(e == ee);
    if (ee == e) rank = __popcll(m & lmask);
    if (l == 0) wcnt[w][ee] = __popcll(m);
  }
  __syncthreads();
  if (tid < NEXP) {
    int s = 0;
#pragma unroll
    for (int ww = 0; ww < 4; ++ww) { wpre[ww][tid] = s; s += wcnt[ww][tid]; }
    base[tid] = meta[16 + tid] + atomicAdd(&meta[8 + tid], s);
  }
  __syncthreads();
  int pos = base[e] + wpre[w][e] + rank;
  perm[pos] = i >> 1;
  slot[i] = pos;
}

// ---------- 5. fp32 -> bf16 convert (weights) ----------
__global__ __launch_bounds__(256) void cvt_kernel(const float* __restrict__ in,
                                                  u16* __restrict__ out) {
  int i = (blockIdx.x * 256 + threadIdx.x) * 4;
  float4 v = *(const float4*)(in + i);
  u16x4 o;
  o.x = f2bf(v.x); o.y = f2bf(v.y); o.z = f2bf(v.z); o.w = f2bf(v.w);
  *(u16x4*)(out + i) = o;
}

// ---------- 6/7. grouped GEMM: 8 waves / 512 threads, counted-vmcnt ----
// Wave grid 2(M) x 4(N): wave = MW x 32 output (MW = TBM/2).
// Grid decode:
//   PF=2 (G1): 2-D grid, u = blockIdx.x (tile), panel = blockIdx.y
//   PF=1 (G2): 1-D grid, bijective XCD-chunk swizzle, panel-fastest
#define STAGE_TILE(buf, kt)                                    \
  do {                                                         \
    char* al_ = albase + (buf) * (TBM * 128);                  \
    char* bl_ = blbase + (buf) * 16384;                        \
    _Pragma("unroll") for (int i_ = 0; i_ < LA; ++i_)          \
      async16(asrc[i_] + (kt), al_ + i_ * 8192);               \
    _Pragma("unroll") for (int i_ = 0; i_ < 2; ++i_)           \
      async16(bsrc[i_] + (kt), bl_ + i_ * 8192);               \
  } while (0)

#define COMPUTE_TILE(buf)                                                      \
  do {                                                                         \
    _Pragma("unroll") for (int kk_ = 0; kk_ < 64; kk_ += 32) {                 \
      bf16x8 af_[MFR], bf_[2];                                                 \
      _Pragma("unroll") for (int m_ = 0; m_ < MFR; ++m_)                       \
        af_[m_] = *(const bf16x8*)&As[buf][(wr * MW + m_ * 16 + lr) * 64 +     \
                                          kk_ + lk * 8];                       \
      _Pragma("unroll") for (int n_ = 0; n_ < 2; ++n_)                         \
        bf_[n_] = *(const bf16x8*)&Bs[buf][(wc * 32 + n_ * 16 + lr) * 64 +     \
                                           kk_ + lk * 8];                      \
      _Pragma("unroll") for (int m_ = 0; m_ < MFR; ++m_)                       \
        _Pragma("unroll") for (int n_ = 0; n_ < 2; ++n_)                       \
          acc[m_][n_] = __builtin_amdgcn_mfma_f32_16x16x32_bf16(               \
              af_[m_], bf_[n_], acc[m_][n_], 0, 0, 0);                         \
    }                                                                          \
  } while (0)

template <int TBM, int PF>
__global__ __launch_bounds__(512) void gemm_kernel(
    const u16* __restrict__ A, int Astride, const int* __restrict__ perm, int Arowoff,
    const u16* __restrict__ B, int Bstride, size_t Bexp,
    u16* __restrict__ C, int Cstride, int Crowoff, int gelu, int K, int t0,
    int NP, int NU, const int* __restrict__ meta) {
  constexpr int MW  = TBM / 2;      // rows per wave: 64 or 32
  constexpr int MFR = MW / 16;      // m-frags: 4 or 2
  constexpr int LA  = TBM / 64;     // A stage loads/thread: 2 or 1
  constexpr int NLD = LA + 2;       // vmem instrs per stage: 4 or 3

  int u, panel;
  if (PF == 2) {
    u = blockIdx.x; panel = blockIdx.y;
  } else {
    // bijective XCD-chunk swizzle (gridDim.x % 8 == 0)
    int nwg = gridDim.x;
    int id = ((int)blockIdx.x & 7) * (nwg >> 3) + ((int)blockIdx.x >> 3);
    u = id / NP; panel = id % NP;
  }
  int tile = t0 + ((TBM == 128) ? u : (u >> 1));
  if (tile >= meta[24]) return;
  int e  = meta[META_TE + tile];
  int m0 = meta[META_TR + tile] + ((TBM == 64) ? (u & 1) * 64 : 0);
  const u16* Be = B + (size_t)e * Bexp;

  __shared__ __align__(16) u16 As[2][TBM * 64];   // 2x16KB or 2x8KB
  __shared__ __align__(16) u16 Bs[2][128 * 64];   // 2x16KB

  int tid = threadIdx.x, l = tid & 63, w = tid >> 6;
  int wr = w >> 2, wc = w & 3;
  int lr = l & 15, lk = l >> 4;

  f32x4 acc[MFR][2] = {};

  const u16* asrc[LA];
  const u16* bsrc[2];
#pragma unroll
  for (int i = 0; i < LA; ++i) {
    int r = i * 64 + (tid >> 3);
    int gr = m0 + r;
    if (perm) gr = perm[gr]; else gr -= Arowoff;
    asrc[i] = A + (size_t)gr * Astride + (tid & 7) * 8;
  }
#pragma unroll
  for (int i = 0; i < 2; ++i) {
    int br = panel * 128 + i * 64 + (tid >> 3);
    bsrc[i] = Be + (size_t)br * Bstride + (tid & 7) * 8;
  }
  char* albase = (char*)&As[0][0] + w * 1024 + l * 16;
  char* blbase = (char*)&Bs[0][0] + w * 1024 + l * 16;

  // ---- counted-vmcnt software pipeline (T4)
  const int S = K >> 6;          // K-steps (8 for G1, 32 for G2)
  STAGE_TILE(0, 0);
  if (S > 1) STAGE_TILE(1, 64);
  int cur = 0;
  for (int s = 0; s < S; ++s) {
    if (s + 1 < S) wait_vm<NLD>(); else wait_vm<0>();
    __builtin_amdgcn_s_barrier();          // all waves' stage for buf cur done
    __builtin_amdgcn_sched_barrier(0);
    COMPUTE_TILE(cur);
    if (s + 2 < S) {
      __builtin_amdgcn_sched_barrier(0);
      __builtin_amdgcn_s_barrier();        // all waves done reading buf cur
      STAGE_TILE(cur, (s + 2) * 64);       // restage into cur for step s+2
    }
    cur ^= 1;
  }

  // scalar epilogue: C/D layout col = lane&15, row = (lane>>4)*4 + reg
#pragma unroll
  for (int m = 0; m < MFR; ++m) {
    int row = m0 - Crowoff + wr * MW + m * 16 + lk * 4;
#pragma unroll
    for (int j = 0; j < 4; ++j) {
      size_t rbase = (size_t)(row + j) * Cstride + panel * 128 + wc * 32;
#pragma unroll
      for (int n = 0; n < 2; ++n) {
        float v = acc[m][n][j];
        if (gelu) {
          // tanh-form GELU in sigmoid formulation (overflow-safe)
          float t = 1.5957691216f * (v + 0.044715f * v * v * v);
          v = v / (1.0f + __expf(-t));
        }
        C[rbase + n * 16 + lr] = f2bf(v);
      }
    }
  }
}
#undef STAGE_TILE
#undef COMPUTE_TILE

// ---------- 8. combine: out = g0*h2[s0] + g1*h2[s1] ----------
__global__ __launch_bounds__(256) void combine_kernel(
    const u16* __restrict__ h2, const int* __restrict__ slot,
    const float* __restrict__ gat, float* __restrict__ out) {
  int i = blockIdx.x * 256 + threadIdx.x;  // over N*512/8
  int t = i >> 6;
  int c = (i & 63) * 8;
  int s0 = slot[t * 2], s1 = slot[t * 2 + 1];
  float g0 = gat[t * 2], g1 = gat[t * 2 + 1];
  bf16x8 a = *(const bf16x8*)&h2[(size_t)s0 * DIMD + c];
  bf16x8 b = *(const bf16x8*)&h2[(size_t)s1 * DIMD + c];
  float4 o0, o1;
  o0.x = g0 * bf2f(a[0]) + g1 * bf2f(b[0]);
  o0.y = g0 * bf2f(a[1]) + g1 * bf2f(b[1]);
  o0.z = g0 * bf2f(a[2]) + g1 * bf2f(b[2]);
  o0.w = g0 * bf2f(a[3]) + g1 * bf2f(b[3]);
  o1.x = g0 * bf2f(a[4]) + g1 * bf2f(b[4]);
  o1.y = g0 * bf2f(a[5]) + g1 * bf2f(b[5]);
  o1.z = g0 * bf2f(a[6]) + g1 * bf2f(b[6]);
  o1.w = g0 * bf2f(a[7]) + g1 * bf2f(b[7]);
  float* op = out + (size_t)t * DIMD + c;
  *(float4*)op = o0;
  *(float4*)(op + 4) = o1;
}

extern "C" void kernel_launch(void* const* d_in, const int* in_sizes, int n_in,
                              void* d_out, int out_size, void* d_ws, size_t ws_size,
                              hipStream_t stream) {
  const float* x  = (const float*)d_in[0];
  const float* Wr = (const float*)d_in[1];
  const float* W1 = (const float*)d_in[2];
  const float* W2 = (const float*)d_in[3];
  float* out = (float*)d_out;
  char* ws = (char*)d_ws;

  // workspace layout — total 204,481,024 B (known to fit)
  u16*   xb   = (u16*)(ws);                      // 33,554,432
  u16*   W1b  = (u16*)(ws + 33554432ull);        // 16,777,216
  u16*   W2b  = (u16*)(ws + 50331648ull);        // 16,777,216
  int*   eidx = (int*)(ws + 67108864ull);        // 262,144
  float* gat  = (float*)(ws + 67371008ull);      // 262,144
  int*   slot = (int*)(ws + 67633152ull);        // 262,144
  int*   perm = (int*)(ws + 67895296ull);        // 266,240
  int*   meta = (int*)(ws + 68161536ull);        // 4,608
  u16*   h2   = (u16*)(ws + 68166144ull);        // 68,157,440 (PADMAX*512*2)
  u16*   hc   = (u16*)(ws + 136323584ull);       // 68,157,440 (TPC*128*2048*2)

  if (ws_size < 204481024ull) {
    fprintf(stderr, "[moe kernel] ws_size=%zu too small (need 204481024)\n", ws_size);
    return;
  }

  init_kernel<<<1, 64, 0, stream>>>(meta);
  router_kernel<<<NTOK / 4, 256, 0, stream>>>(x, Wr, xb, eidx, gat);
  count_kernel<<<(NTOK * 2) / 256, 256, 0, stream>>>(eidx, meta);
  scan_kernel<<<1, 256, 0, stream>>>(meta, perm);
  scatter_kernel<<<(NTOK * 2) / 256, 256, 0, stream>>>(eidx, meta, perm, slot);

  cvt_kernel<<<(NEXP * FFD * DIMD) / 1024, 256, 0, stream>>>(W1, W1b);
  cvt_kernel<<<(NEXP * DIMD * FFD) / 1024, 256, 0, stream>>>(W2, W2b);

  for (int c = 0; c < NCHUNK; ++c) {
    int t0 = c * TPC;
    // GEMM1: hc[slot-t0*128][0:2048] = gelu( xb[perm[slot]] @ W1[e]^T ), K=512
    gemm_kernel<128, 2><<<dim3(TPC, FFD / 128), 512, 0, stream>>>(
        xb, DIMD, perm, 0,
        W1b, DIMD, (size_t)FFD * DIMD,
        hc, FFD, t0 * BM, 1, DIMD, t0, FFD / 128, TPC, meta);
    // GEMM2: h2[slot][0:512] = hc[slot-t0*128] @ W2[e]^T, K=2048 (64-row units)
    gemm_kernel<64, 1><<<TPC * 2 * (DIMD / 128), 512, 0, stream>>>(
        hc, FFD, nullptr, t0 * BM,
        W2b, FFD, (size_t)DIMD * FFD,
        h2, DIMD, 0, 0, FFD, t0, DIMD / 128, TPC * 2, meta);
  }

  combine_kernel<<<(NTOK * DIMD) / 8 / 256, 256, 0, stream>>>(h2, slot, gat, out);
}

// Round 12
// 611.801 us; speedup vs baseline: 1.2587x; 1.2587x over previous
//
#include <hip/hip_runtime.h>
#include <hip/hip_bf16.h>
#include <math.h>
#include <stdint.h>
#include <stdio.h>

#define DIMD 512
#define FFD  2048
#define NEXP 8
#define NTOK 32768          // 8*4096 tokens
#define BM   128            // m-tile granularity of the tile map
#define MAXT 520            // max m-tiles: 65536/128 + 8
#define PADMAX (MAXT * BM)  // 66560 padded slots
#define NCHUNK 4
#define TPC    130          // tiles per chunk (MAXT/NCHUNK)

typedef unsigned short u16;
typedef __attribute__((ext_vector_type(8))) short bf16x8;
typedef __attribute__((ext_vector_type(4))) float f32x4;
typedef __attribute__((ext_vector_type(4))) unsigned short u16x4;

// meta layout (ints): [0..7] counts, [8..15] fills, [16..23] seg starts,
// [24] numTiles, [32..32+MAXT) tileExpert, [560..560+MAXT) tileRow
#define META_TE   32
#define META_TR   560

__device__ __forceinline__ void async16(const void* g, void* l) {
  __builtin_amdgcn_global_load_lds(
      (const __attribute__((address_space(1))) unsigned int*)g,
      (__attribute__((address_space(3))) unsigned int*)l, 16, 0, 0);
}

__device__ __forceinline__ float bf2f(short s) {
  unsigned int u = ((unsigned int)(u16)s) << 16;
  return __uint_as_float(u);
}
__device__ __forceinline__ u16 f2bf(float f) {
  __hip_bfloat16 h = __float2bfloat16(f);
  return *(u16*)&h;
}

// counted vmcnt wait (compile-time literal per T4 discipline)
template <int N>
__device__ __forceinline__ void wait_vm() {
  if constexpr (N == 0)      asm volatile("s_waitcnt vmcnt(0)" ::: "memory");
  else if constexpr (N == 3) asm volatile("s_waitcnt vmcnt(3)" ::: "memory");
  else if constexpr (N == 4) asm volatile("s_waitcnt vmcnt(4)" ::: "memory");
  else if constexpr (N == 6) asm volatile("s_waitcnt vmcnt(6)" ::: "memory");
  else                       asm volatile("s_waitcnt vmcnt(8)" ::: "memory");
}

// ---------- 1. zero the atomic counters ----------
__global__ void init_kernel(int* __restrict__ meta) {
  if (threadIdx.x < 16) meta[threadIdx.x] = 0;
}

// ---------- 2. router + x->bf16: 4 waves/block, 1 token/wave, coalesced.
// fp64 logits, deterministic butterfly reduce, top-2 softmax gates.
__global__ __launch_bounds__(256) void router_kernel(
    const float* __restrict__ x, const float* __restrict__ Wr,
    u16* __restrict__ xb, int* __restrict__ eidx, float* __restrict__ gat) {
  __shared__ float wrs[NEXP * DIMD];  // 16 KB
  int tid = threadIdx.x, l = tid & 63, w = tid >> 6;
  for (int i = tid * 4; i < NEXP * DIMD; i += 1024)
    *(float4*)&wrs[i] = *(const float4*)&Wr[i];
  __syncthreads();

  int t = blockIdx.x * 4 + w;
  const float* xr = x + (size_t)t * DIMD + l * 8;
  float4 a = *(const float4*)xr;
  float4 b = *(const float4*)(xr + 4);

  // fused x -> bf16 (coalesced 16B/lane)
  bf16x8 xo;
  xo[0] = (short)f2bf(a.x); xo[1] = (short)f2bf(a.y);
  xo[2] = (short)f2bf(a.z); xo[3] = (short)f2bf(a.w);
  xo[4] = (short)f2bf(b.x); xo[5] = (short)f2bf(b.y);
  xo[6] = (short)f2bf(b.z); xo[7] = (short)f2bf(b.w);
  *(bf16x8*)&xb[(size_t)t * DIMD + l * 8] = xo;

  double p[NEXP];
#pragma unroll
  for (int e = 0; e < NEXP; ++e) {
    const float* wr = &wrs[e * DIMD + l * 8];
    p[e] = (double)a.x * wr[0] + (double)a.y * wr[1] +
           (double)a.z * wr[2] + (double)a.w * wr[3] +
           (double)b.x * wr[4] + (double)b.y * wr[5] +
           (double)b.z * wr[6] + (double)b.w * wr[7];
  }
#pragma unroll
  for (int off = 1; off < 64; off <<= 1) {
#pragma unroll
    for (int e = 0; e < NEXP; ++e) p[e] += __shfl_xor(p[e], off);
  }
  if (l == 0) {
    int b0 = 0; double v0 = p[0];
#pragma unroll
    for (int e = 1; e < NEXP; ++e) if (p[e] > v0) { v0 = p[e]; b0 = e; }
    int b1 = -1; double v1 = -1e300;
#pragma unroll
    for (int e = 0; e < NEXP; ++e) {
      if (e == b0) continue;
      if (b1 < 0 || p[e] > v1) { v1 = p[e]; b1 = e; }
    }
    float e1 = expf((float)(v1 - v0));
    float inv = 1.0f / (1.0f + e1);
    eidx[t * 2] = b0; eidx[t * 2 + 1] = b1;
    gat[t * 2] = inv; gat[t * 2 + 1] = e1 * inv;
  }
}

// ---------- 2b. expert histogram with LDS pre-aggregation ----------
__global__ __launch_bounds__(256) void count_kernel(const int* __restrict__ eidx,
                                                    int* __restrict__ meta) {
  __shared__ int h[NEXP];
  if (threadIdx.x < NEXP) h[threadIdx.x] = 0;
  __syncthreads();
  int i = blockIdx.x * 256 + threadIdx.x;  // over NTOK*2
  atomicAdd(&h[eidx[i]], 1);
  __syncthreads();
  if (threadIdx.x < NEXP) atomicAdd(&meta[threadIdx.x], h[threadIdx.x]);
}

// ---------- 3. scan: segment starts (128-aligned), tile map, pad perm ----------
__global__ void scan_kernel(int* __restrict__ meta, int* __restrict__ perm) {
  __shared__ int s_start[NEXP], s_cnt[NEXP], s_tiles[NEXP];
  __shared__ int s_tbase[NEXP];
  if (threadIdx.x == 0) {
    int cum = 0, tb = 0;
    for (int e = 0; e < NEXP; ++e) {
      int c = meta[e];
      s_cnt[e] = c; s_start[e] = cum; s_tbase[e] = tb;
      meta[16 + e] = cum;
      int nt = (c + BM - 1) / BM;
      s_tiles[e] = nt;
      tb += nt;
      cum += nt * BM;
    }
    meta[24] = tb;
  }
  __syncthreads();
  for (int e = 0; e < NEXP; ++e) {
    for (int i = threadIdx.x; i < s_tiles[e]; i += blockDim.x) {
      meta[META_TE + s_tbase[e] + i] = e;
      meta[META_TR + s_tbase[e] + i] = s_start[e] + i * BM;
    }
    int npad = s_tiles[e] * BM - s_cnt[e];
    for (int i = threadIdx.x; i < npad; i += blockDim.x)
      perm[s_start[e] + s_cnt[e] + i] = 0;   // pad slots point at token 0
  }
}

// ---------- 4. scatter: slot assignment, block-aggregated atomics ----------
__global__ __launch_bounds__(256) void scatter_kernel(
    const int* __restrict__ eidx, int* __restrict__ meta,
    int* __restrict__ perm, int* __restrict__ slot) {
  __shared__ int wcnt[4][NEXP], wpre[4][NEXP], base[NEXP];
  int tid = threadIdx.x, l = tid & 63, w = tid >> 6;
  int i = blockIdx.x * 256 + tid;  // over NTOK*2
  int e = eidx[i];
  unsigned long long lmask = (l == 63) ? ~0ull >> 1 : ((1ull << l) - 1);
  int rank = 0;
#pragma unroll
  for (int ee = 0; ee < NEXP; ++ee) {
    unsigned long long m = __ballot(e == ee);
    if (ee == e) rank = __popcll(m & lmask);
    if (l == 0) wcnt[w][ee] = __popcll(m);
  }
  __syncthreads();
  if (tid < NEXP) {
    int s = 0;
#pragma unroll
    for (int ww = 0; ww < 4; ++ww) { wpre[ww][tid] = s; s += wcnt[ww][tid]; }
    base[tid] = meta[16 + tid] + atomicAdd(&meta[8 + tid], s);
  }
  __syncthreads();
  int pos = base[e] + wpre[w][e] + rank;
  perm[pos] = i >> 1;
  slot[i] = pos;
}

// ---------- 5. fp32 -> bf16 convert (weights) ----------
__global__ __launch_bounds__(256) void cvt_kernel(const float* __restrict__ in,
                                                  u16* __restrict__ out) {
  int i = (blockIdx.x * 256 + threadIdx.x) * 4;
  float4 v = *(const float4*)(in + i);
  u16x4 o;
  o.x = f2bf(v.x); o.y = f2bf(v.y); o.z = f2bf(v.z); o.w = f2bf(v.w);
  *(u16x4*)(out + i) = o;
}

// ---------- 6/7. grouped GEMM: 8 waves / 512 threads, counted-vmcnt,
//                T2 XOR-swizzled LDS (pre-swizzled global source) ----
// LDS tile rows are 128B (8 x 16B slots). Staging thread t loads GLOBAL
// slot (t&7)^(row&7) into LINEAR LDS slot t&7; reads XOR the same way:
// physical slot = logical ^ (row&7). 16 lanes/column-slice now spread
// over 8 banks x 2 lanes (2-way = free) instead of 16-way.
#define STAGE_TILE(buf, kt)                                    \
  do {                                                         \
    char* al_ = albase + (buf) * (TBM * 128);                  \
    char* bl_ = blbase + (buf) * 16384;                        \
    _Pragma("unroll") for (int i_ = 0; i_ < LA; ++i_)          \
      async16(asrc[i_] + (kt), al_ + i_ * 8192);               \
    _Pragma("unroll") for (int i_ = 0; i_ < 2; ++i_)           \
      async16(bsrc[i_] + (kt), bl_ + i_ * 8192);               \
  } while (0)

#define COMPUTE_TILE(buf)                                                      \
  do {                                                                         \
    _Pragma("unroll") for (int kk_ = 0; kk_ < 2; ++kk_) {                      \
      bf16x8 af_[MFR], bf_[2];                                                 \
      int cb_ = ((kk_ << 2) + lk) ^ (lr & 7);                                  \
      _Pragma("unroll") for (int m_ = 0; m_ < MFR; ++m_)                       \
        af_[m_] = *(const bf16x8*)&As[buf][(wr * MW + m_ * 16 + lr) * 64 +     \
                                          cb_ * 8];                            \
      _Pragma("unroll") for (int n_ = 0; n_ < 2; ++n_)                         \
        bf_[n_] = *(const bf16x8*)&Bs[buf][(wc * 32 + n_ * 16 + lr) * 64 +     \
                                           cb_ * 8];                           \
      _Pragma("unroll") for (int m_ = 0; m_ < MFR; ++m_)                       \
        _Pragma("unroll") for (int n_ = 0; n_ < 2; ++n_)                       \
          acc[m_][n_] = __builtin_amdgcn_mfma_f32_16x16x32_bf16(               \
              af_[m_], bf_[n_], acc[m_][n_], 0, 0, 0);                         \
    }                                                                          \
  } while (0)

template <int TBM, int PF>
__global__ __launch_bounds__(512) void gemm_kernel(
    const u16* __restrict__ A, int Astride, const int* __restrict__ perm, int Arowoff,
    const u16* __restrict__ B, int Bstride, size_t Bexp,
    u16* __restrict__ C, int Cstride, int Crowoff, int gelu, int K, int t0,
    int NP, int NU, const int* __restrict__ meta) {
  constexpr int MW  = TBM / 2;      // rows per wave: 64 or 32
  constexpr int MFR = MW / 16;      // m-frags: 4 or 2
  constexpr int LA  = TBM / 64;     // A stage loads/thread: 2 or 1
  constexpr int NLD = LA + 2;       // vmem instrs per stage: 4 or 3

  int u, panel;
  if (PF == 2) {
    u = blockIdx.x; panel = blockIdx.y;
  } else {
    // bijective XCD-chunk swizzle (gridDim.x % 8 == 0)
    int nwg = gridDim.x;
    int id = ((int)blockIdx.x & 7) * (nwg >> 3) + ((int)blockIdx.x >> 3);
    u = id / NP; panel = id % NP;
  }
  int tile = t0 + ((TBM == 128) ? u : (u >> 1));
  if (tile >= meta[24]) return;
  int e  = meta[META_TE + tile];
  int m0 = meta[META_TR + tile] + ((TBM == 64) ? (u & 1) * 64 : 0);
  const u16* Be = B + (size_t)e * Bexp;

  __shared__ __align__(16) u16 As[2][TBM * 64];   // 2x16KB or 2x8KB
  __shared__ __align__(16) u16 Bs[2][128 * 64];   // 2x16KB

  int tid = threadIdx.x, l = tid & 63, w = tid >> 6;
  int wr = w >> 2, wc = w & 3;
  int lr = l & 15, lk = l >> 4;

  f32x4 acc[MFR][2] = {};

  // T2: pre-swizzled global source column slot (involution per 8-slot row)
  int swz = (((tid & 7) ^ ((tid >> 3) & 7))) * 8;

  const u16* asrc[LA];
  const u16* bsrc[2];
#pragma unroll
  for (int i = 0; i < LA; ++i) {
    int r = i * 64 + (tid >> 3);
    int gr = m0 + r;
    if (perm) gr = perm[gr]; else gr -= Arowoff;
    asrc[i] = A + (size_t)gr * Astride + swz;
  }
#pragma unroll
  for (int i = 0; i < 2; ++i) {
    int br = panel * 128 + i * 64 + (tid >> 3);
    bsrc[i] = Be + (size_t)br * Bstride + swz;
  }
  char* albase = (char*)&As[0][0] + w * 1024 + l * 16;
  char* blbase = (char*)&Bs[0][0] + w * 1024 + l * 16;

  // ---- counted-vmcnt software pipeline (T4)
  const int S = K >> 6;          // K-steps (8 for G1, 32 for G2)
  STAGE_TILE(0, 0);
  if (S > 1) STAGE_TILE(1, 64);
  int cur = 0;
  for (int s = 0; s < S; ++s) {
    if (s + 1 < S) wait_vm<NLD>(); else wait_vm<0>();
    __builtin_amdgcn_s_barrier();          // all waves' stage for buf cur done
    __builtin_amdgcn_sched_barrier(0);
    COMPUTE_TILE(cur);
    if (s + 2 < S) {
      __builtin_amdgcn_sched_barrier(0);
      __builtin_amdgcn_s_barrier();        // all waves done reading buf cur
      STAGE_TILE(cur, (s + 2) * 64);       // restage into cur for step s+2
    }
    cur ^= 1;
  }

  // scalar epilogue: C/D layout col = lane&15, row = (lane>>4)*4 + reg
#pragma unroll
  for (int m = 0; m < MFR; ++m) {
    int row = m0 - Crowoff + wr * MW + m * 16 + lk * 4;
#pragma unroll
    for (int j = 0; j < 4; ++j) {
      size_t rbase = (size_t)(row + j) * Cstride + panel * 128 + wc * 32;
#pragma unroll
      for (int n = 0; n < 2; ++n) {
        float v = acc[m][n][j];
        if (gelu) {
          // tanh-form GELU in sigmoid formulation (overflow-safe)
          float t = 1.5957691216f * (v + 0.044715f * v * v * v);
          v = v / (1.0f + __expf(-t));
        }
        C[rbase + n * 16 + lr] = f2bf(v);
      }
    }
  }
}
#undef STAGE_TILE
#undef COMPUTE_TILE

// ---------- 8. combine: out = g0*h2[s0] + g1*h2[s1] ----------
__global__ __launch_bounds__(256) void combine_kernel(
    const u16* __restrict__ h2, const int* __restrict__ slot,
    const float* __restrict__ gat, float* __restrict__ out) {
  int i = blockIdx.x * 256 + threadIdx.x;  // over N*512/8
  int t = i >> 6;
  int c = (i & 63) * 8;
  int s0 = slot[t * 2], s1 = slot[t * 2 + 1];
  float g0 = gat[t * 2], g1 = gat[t * 2 + 1];
  bf16x8 a = *(const bf16x8*)&h2[(size_t)s0 * DIMD + c];
  bf16x8 b = *(const bf16x8*)&h2[(size_t)s1 * DIMD + c];
  float4 o0, o1;
  o0.x = g0 * bf2f(a[0]) + g1 * bf2f(b[0]);
  o0.y = g0 * bf2f(a[1]) + g1 * bf2f(b[1]);
  o0.z = g0 * bf2f(a[2]) + g1 * bf2f(b[2]);
  o0.w = g0 * bf2f(a[3]) + g1 * bf2f(b[3]);
  o1.x = g0 * bf2f(a[4]) + g1 * bf2f(b[4]);
  o1.y = g0 * bf2f(a[5]) + g1 * bf2f(b[5]);
  o1.z = g0 * bf2f(a[6]) + g1 * bf2f(b[6]);
  o1.w = g0 * bf2f(a[7]) + g1 * bf2f(b[7]);
  float* op = out + (size_t)t * DIMD + c;
  *(float4*)op = o0;
  *(float4*)(op + 4) = o1;
}

extern "C" void kernel_launch(void* const* d_in, const int* in_sizes, int n_in,
                              void* d_out, int out_size, void* d_ws, size_t ws_size,
                              hipStream_t stream) {
  const float* x  = (const float*)d_in[0];
  const float* Wr = (const float*)d_in[1];
  const float* W1 = (const float*)d_in[2];
  const float* W2 = (const float*)d_in[3];
  float* out = (float*)d_out;
  char* ws = (char*)d_ws;

  // workspace layout — total 204,481,024 B (known to fit)
  u16*   xb   = (u16*)(ws);                      // 33,554,432
  u16*   W1b  = (u16*)(ws + 33554432ull);        // 16,777,216
  u16*   W2b  = (u16*)(ws + 50331648ull);        // 16,777,216
  int*   eidx = (int*)(ws + 67108864ull);        // 262,144
  float* gat  = (float*)(ws + 67371008ull);      // 262,144
  int*   slot = (int*)(ws + 67633152ull);        // 262,144
  int*   perm = (int*)(ws + 67895296ull);        // 266,240
  int*   meta = (int*)(ws + 68161536ull);        // 4,608
  u16*   h2   = (u16*)(ws + 68166144ull);        // 68,157,440 (PADMAX*512*2)
  u16*   hc   = (u16*)(ws + 136323584ull);       // 68,157,440 (TPC*128*2048*2)

  if (ws_size < 204481024ull) {
    fprintf(stderr, "[moe kernel] ws_size=%zu too small (need 204481024)\n", ws_size);
    return;
  }

  init_kernel<<<1, 64, 0, stream>>>(meta);
  router_kernel<<<NTOK / 4, 256, 0, stream>>>(x, Wr, xb, eidx, gat);
  count_kernel<<<(NTOK * 2) / 256, 256, 0, stream>>>(eidx, meta);
  scan_kernel<<<1, 256, 0, stream>>>(meta, perm);
  scatter_kernel<<<(NTOK * 2) / 256, 256, 0, stream>>>(eidx, meta, perm, slot);

  cvt_kernel<<<(NEXP * FFD * DIMD) / 1024, 256, 0, stream>>>(W1, W1b);
  cvt_kernel<<<(NEXP * DIMD * FFD) / 1024, 256, 0, stream>>>(W2, W2b);

  for (int c = 0; c < NCHUNK; ++c) {
    int t0 = c * TPC;
    // GEMM1: hc[slot-t0*128][0:2048] = gelu( xb[perm[slot]] @ W1[e]^T ), K=512
    gemm_kernel<128, 2><<<dim3(TPC, FFD / 128), 512, 0, stream>>>(
        xb, DIMD, perm, 0,
        W1b, DIMD, (size_t)FFD * DIMD,
        hc, FFD, t0 * BM, 1, DIMD, t0, FFD / 128, TPC, meta);
    // GEMM2: h2[slot][0:512] = hc[slot-t0*128] @ W2[e]^T, K=2048 (64-row units)
    gemm_kernel<64, 1><<<TPC * 2 * (DIMD / 128), 512, 0, stream>>>(
        hc, FFD, nullptr, t0 * BM,
        W2b, FFD, (size_t)DIMD * FFD,
        h2, DIMD, 0, 0, FFD, t0, DIMD / 128, TPC * 2, meta);
  }

  combine_kernel<<<(NTOK * DIMD) / 8 / 256, 256, 0, stream>>>(h2, slot, gat, out);
}

// Round 13
// 567.309 us; speedup vs baseline: 1.3574x; 1.0784x over previous
//
#include <hip/hip_runtime.h>
#include <hip/hip_bf16.h>
#include <math.h>
#include <stdint.h>
#include <stdio.h>

#define DIMD 512
#define FFD  2048
#define NEXP 8
#define NTOK 32768          // 8*4096 tokens
#define BM   128            // m-tile granularity of the tile map
#define MAXT 520            // max m-tiles: 65536/128 + 8
#define PADMAX (MAXT * BM)  // 66560 padded slots
#define NCHUNK 4
#define TPC    130          // tiles per chunk (MAXT/NCHUNK)

typedef unsigned short u16;
typedef __attribute__((ext_vector_type(8))) short bf16x8;
typedef __attribute__((ext_vector_type(4))) float f32x4;
typedef __attribute__((ext_vector_type(4))) unsigned short u16x4;

// meta layout (ints): [0..7] counts, [8..15] fills, [16..23] seg starts,
// [24] numTiles, [32..32+MAXT) tileExpert, [560..560+MAXT) tileRow
#define META_TE   32
#define META_TR   560

__device__ __forceinline__ void async16(const void* g, void* l) {
  __builtin_amdgcn_global_load_lds(
      (const __attribute__((address_space(1))) unsigned int*)g,
      (__attribute__((address_space(3))) unsigned int*)l, 16, 0, 0);
}

__device__ __forceinline__ float bf2f(short s) {
  unsigned int u = ((unsigned int)(u16)s) << 16;
  return __uint_as_float(u);
}
__device__ __forceinline__ u16 f2bf(float f) {
  __hip_bfloat16 h = __float2bfloat16(f);
  return *(u16*)&h;
}

// counted vmcnt wait (compile-time literal per T4 discipline)
template <int N>
__device__ __forceinline__ void wait_vm() {
  if constexpr (N == 0)      asm volatile("s_waitcnt vmcnt(0)" ::: "memory");
  else if constexpr (N == 3) asm volatile("s_waitcnt vmcnt(3)" ::: "memory");
  else if constexpr (N == 4) asm volatile("s_waitcnt vmcnt(4)" ::: "memory");
  else if constexpr (N == 6) asm volatile("s_waitcnt vmcnt(6)" ::: "memory");
  else                       asm volatile("s_waitcnt vmcnt(8)" ::: "memory");
}

// ---------- 1. zero the atomic counters ----------
__global__ void init_kernel(int* __restrict__ meta) {
  if (threadIdx.x < 16) meta[threadIdx.x] = 0;
}

// ---------- 2. router + x->bf16: 4 waves/block, 1 token/wave, coalesced.
// fp64 logits, deterministic butterfly reduce, top-2 softmax gates.
__global__ __launch_bounds__(256) void router_kernel(
    const float* __restrict__ x, const float* __restrict__ Wr,
    u16* __restrict__ xb, int* __restrict__ eidx, float* __restrict__ gat) {
  __shared__ float wrs[NEXP * DIMD];  // 16 KB
  int tid = threadIdx.x, l = tid & 63, w = tid >> 6;
  for (int i = tid * 4; i < NEXP * DIMD; i += 1024)
    *(float4*)&wrs[i] = *(const float4*)&Wr[i];
  __syncthreads();

  int t = blockIdx.x * 4 + w;
  const float* xr = x + (size_t)t * DIMD + l * 8;
  float4 a = *(const float4*)xr;
  float4 b = *(const float4*)(xr + 4);

  // fused x -> bf16 (coalesced 16B/lane)
  bf16x8 xo;
  xo[0] = (short)f2bf(a.x); xo[1] = (short)f2bf(a.y);
  xo[2] = (short)f2bf(a.z); xo[3] = (short)f2bf(a.w);
  xo[4] = (short)f2bf(b.x); xo[5] = (short)f2bf(b.y);
  xo[6] = (short)f2bf(b.z); xo[7] = (short)f2bf(b.w);
  *(bf16x8*)&xb[(size_t)t * DIMD + l * 8] = xo;

  double p[NEXP];
#pragma unroll
  for (int e = 0; e < NEXP; ++e) {
    const float* wr = &wrs[e * DIMD + l * 8];
    p[e] = (double)a.x * wr[0] + (double)a.y * wr[1] +
           (double)a.z * wr[2] + (double)a.w * wr[3] +
           (double)b.x * wr[4] + (double)b.y * wr[5] +
           (double)b.z * wr[6] + (double)b.w * wr[7];
  }
#pragma unroll
  for (int off = 1; off < 64; off <<= 1) {
#pragma unroll
    for (int e = 0; e < NEXP; ++e) p[e] += __shfl_xor(p[e], off);
  }
  if (l == 0) {
    int b0 = 0; double v0 = p[0];
#pragma unroll
    for (int e = 1; e < NEXP; ++e) if (p[e] > v0) { v0 = p[e]; b0 = e; }
    int b1 = -1; double v1 = -1e300;
#pragma unroll
    for (int e = 0; e < NEXP; ++e) {
      if (e == b0) continue;
      if (b1 < 0 || p[e] > v1) { v1 = p[e]; b1 = e; }
    }
    float e1 = expf((float)(v1 - v0));
    float inv = 1.0f / (1.0f + e1);
    eidx[t * 2] = b0; eidx[t * 2 + 1] = b1;
    gat[t * 2] = inv; gat[t * 2 + 1] = e1 * inv;
  }
}

// ---------- 2b. expert histogram with LDS pre-aggregation ----------
__global__ __launch_bounds__(256) void count_kernel(const int* __restrict__ eidx,
                                                    int* __restrict__ meta) {
  __shared__ int h[NEXP];
  if (threadIdx.x < NEXP) h[threadIdx.x] = 0;
  __syncthreads();
  int i = blockIdx.x * 256 + threadIdx.x;  // over NTOK*2
  atomicAdd(&h[eidx[i]], 1);
  __syncthreads();
  if (threadIdx.x < NEXP) atomicAdd(&meta[threadIdx.x], h[threadIdx.x]);
}

// ---------- 3. scan: segment starts (128-aligned), tile map, pad perm ----------
__global__ void scan_kernel(int* __restrict__ meta, int* __restrict__ perm) {
  __shared__ int s_start[NEXP], s_cnt[NEXP], s_tiles[NEXP];
  __shared__ int s_tbase[NEXP];
  if (threadIdx.x == 0) {
    int cum = 0, tb = 0;
    for (int e = 0; e < NEXP; ++e) {
      int c = meta[e];
      s_cnt[e] = c; s_start[e] = cum; s_tbase[e] = tb;
      meta[16 + e] = cum;
      int nt = (c + BM - 1) / BM;
      s_tiles[e] = nt;
      tb += nt;
      cum += nt * BM;
    }
    meta[24] = tb;
  }
  __syncthreads();
  for (int e = 0; e < NEXP; ++e) {
    for (int i = threadIdx.x; i < s_tiles[e]; i += blockDim.x) {
      meta[META_TE + s_tbase[e] + i] = e;
      meta[META_TR + s_tbase[e] + i] = s_start[e] + i * BM;
    }
    int npad = s_tiles[e] * BM - s_cnt[e];
    for (int i = threadIdx.x; i < npad; i += blockDim.x)
      perm[s_start[e] + s_cnt[e] + i] = 0;   // pad slots point at token 0
  }
}

// ---------- 4. scatter: slot assignment, block-aggregated atomics ----------
__global__ __launch_bounds__(256) void scatter_kernel(
    const int* __restrict__ eidx, int* __restrict__ meta,
    int* __restrict__ perm, int* __restrict__ slot) {
  __shared__ int wcnt[4][NEXP], wpre[4][NEXP], base[NEXP];
  int tid = threadIdx.x, l = tid & 63, w = tid >> 6;
  int i = blockIdx.x * 256 + tid;  // over NTOK*2
  int e = eidx[i];
  unsigned long long lmask = (l == 63) ? ~0ull >> 1 : ((1ull << l) - 1);
  int rank = 0;
#pragma unroll
  for (int ee = 0; ee < NEXP; ++ee) {
    unsigned long long m = __ballot(e == ee);
    if (ee == e) rank = __popcll(m & lmask);
    if (l == 0) wcnt[w][ee] = __popcll(m);
  }
  __syncthreads();
  if (tid < NEXP) {
    int s = 0;
#pragma unroll
    for (int ww = 0; ww < 4; ++ww) { wpre[ww][tid] = s; s += wcnt[ww][tid]; }
    base[tid] = meta[16 + tid] + atomicAdd(&meta[8 + tid], s);
  }
  __syncthreads();
  int pos = base[e] + wpre[w][e] + rank;
  perm[pos] = i >> 1;
  slot[i] = pos;
}

// ---------- 5. fp32 -> bf16 convert (weights) ----------
__global__ __launch_bounds__(256) void cvt_kernel(const float* __restrict__ in,
                                                  u16* __restrict__ out) {
  int i = (blockIdx.x * 256 + threadIdx.x) * 4;
  float4 v = *(const float4*)(in + i);
  u16x4 o;
  o.x = f2bf(v.x); o.y = f2bf(v.y); o.z = f2bf(v.z); o.w = f2bf(v.w);
  *(u16x4*)(out + i) = o;
}

// ---------- 6/7. grouped GEMM: 8 waves / 512 threads, counted-vmcnt,
//                T2 XOR-swizzled LDS (pre-swizzled global source) ----
// Both GEMMs: 1-D grid, bijective XCD-chunk swizzle, panel-fastest decode
// (panel varies within consecutive ids -> A-tile L2-resident per XCD,
//  B-panel set (2 MB/expert) L2-resident).
#define STAGE_TILE(buf, kt)                                    \
  do {                                                         \
    char* al_ = albase + (buf) * (TBM * 128);                  \
    char* bl_ = blbase + (buf) * 16384;                        \
    _Pragma("unroll") for (int i_ = 0; i_ < LA; ++i_)          \
      async16(asrc[i_] + (kt), al_ + i_ * 8192);               \
    _Pragma("unroll") for (int i_ = 0; i_ < 2; ++i_)           \
      async16(bsrc[i_] + (kt), bl_ + i_ * 8192);               \
  } while (0)

#define COMPUTE_TILE(buf)                                                      \
  do {                                                                         \
    _Pragma("unroll") for (int kk_ = 0; kk_ < 2; ++kk_) {                      \
      bf16x8 af_[MFR], bf_[2];                                                 \
      int cb_ = ((kk_ << 2) + lk) ^ (lr & 7);                                  \
      _Pragma("unroll") for (int m_ = 0; m_ < MFR; ++m_)                       \
        af_[m_] = *(const bf16x8*)&As[buf][(wr * MW + m_ * 16 + lr) * 64 +     \
                                          cb_ * 8];                            \
      _Pragma("unroll") for (int n_ = 0; n_ < 2; ++n_)                         \
        bf_[n_] = *(const bf16x8*)&Bs[buf][(wc * 32 + n_ * 16 + lr) * 64 +     \
                                           cb_ * 8];                           \
      _Pragma("unroll") for (int m_ = 0; m_ < MFR; ++m_)                       \
        _Pragma("unroll") for (int n_ = 0; n_ < 2; ++n_)                       \
          acc[m_][n_] = __builtin_amdgcn_mfma_f32_16x16x32_bf16(               \
              af_[m_], bf_[n_], acc[m_][n_], 0, 0, 0);                         \
    }                                                                          \
  } while (0)

template <int TBM, int PF>
__global__ __launch_bounds__(512) void gemm_kernel(
    const u16* __restrict__ A, int Astride, const int* __restrict__ perm, int Arowoff,
    const u16* __restrict__ B, int Bstride, size_t Bexp,
    u16* __restrict__ C, int Cstride, int Crowoff, int gelu, int K, int t0,
    int NP, int NU, const int* __restrict__ meta) {
  constexpr int MW  = TBM / 2;      // rows per wave: 64 or 32
  constexpr int MFR = MW / 16;      // m-frags: 4 or 2
  constexpr int LA  = TBM / 64;     // A stage loads/thread: 2 or 1
  constexpr int NLD = LA + 2;       // vmem instrs per stage: 4 or 3

  int u, panel;
  {
    // bijective XCD-chunk swizzle (gridDim.x % 8 == 0), panel-fastest
    int nwg = gridDim.x;
    int id = ((int)blockIdx.x & 7) * (nwg >> 3) + ((int)blockIdx.x >> 3);
    u = id / NP; panel = id % NP;
  }
  int tile = t0 + ((TBM == 128) ? u : (u >> 1));
  if (tile >= meta[24]) return;
  int e  = meta[META_TE + tile];
  int m0 = meta[META_TR + tile] + ((TBM == 64) ? (u & 1) * 64 : 0);
  const u16* Be = B + (size_t)e * Bexp;

  __shared__ __align__(16) u16 As[2][TBM * 64];   // 2x16KB or 2x8KB
  __shared__ __align__(16) u16 Bs[2][128 * 64];   // 2x16KB

  int tid = threadIdx.x, l = tid & 63, w = tid >> 6;
  int wr = w >> 2, wc = w & 3;
  int lr = l & 15, lk = l >> 4;

  f32x4 acc[MFR][2] = {};

  // T2: pre-swizzled global source column slot (involution per 8-slot row)
  int swz = (((tid & 7) ^ ((tid >> 3) & 7))) * 8;

  const u16* asrc[LA];
  const u16* bsrc[2];
#pragma unroll
  for (int i = 0; i < LA; ++i) {
    int r = i * 64 + (tid >> 3);
    int gr = m0 + r;
    if (perm) gr = perm[gr]; else gr -= Arowoff;
    asrc[i] = A + (size_t)gr * Astride + swz;
  }
#pragma unroll
  for (int i = 0; i < 2; ++i) {
    int br = panel * 128 + i * 64 + (tid >> 3);
    bsrc[i] = Be + (size_t)br * Bstride + swz;
  }
  char* albase = (char*)&As[0][0] + w * 1024 + l * 16;
  char* blbase = (char*)&Bs[0][0] + w * 1024 + l * 16;

  // ---- counted-vmcnt software pipeline (T4)
  const int S = K >> 6;          // K-steps (8 for G1, 32 for G2)
  STAGE_TILE(0, 0);
  if (S > 1) STAGE_TILE(1, 64);
  int cur = 0;
  for (int s = 0; s < S; ++s) {
    if (s + 1 < S) wait_vm<NLD>(); else wait_vm<0>();
    __builtin_amdgcn_s_barrier();          // all waves' stage for buf cur done
    __builtin_amdgcn_sched_barrier(0);
    COMPUTE_TILE(cur);
    if (s + 2 < S) {
      __builtin_amdgcn_sched_barrier(0);
      __builtin_amdgcn_s_barrier();        // all waves done reading buf cur
      STAGE_TILE(cur, (s + 2) * 64);       // restage into cur for step s+2
    }
    cur ^= 1;
  }

  // scalar epilogue: C/D layout col = lane&15, row = (lane>>4)*4 + reg
#pragma unroll
  for (int m = 0; m < MFR; ++m) {
    int row = m0 - Crowoff + wr * MW + m * 16 + lk * 4;
#pragma unroll
    for (int j = 0; j < 4; ++j) {
      size_t rbase = (size_t)(row + j) * Cstride + panel * 128 + wc * 32;
#pragma unroll
      for (int n = 0; n < 2; ++n) {
        float v = acc[m][n][j];
        if (gelu) {
          // tanh-form GELU in sigmoid formulation (overflow-safe)
          float t = 1.5957691216f * (v + 0.044715f * v * v * v);
          v = v / (1.0f + __expf(-t));
        }
        C[rbase + n * 16 + lr] = f2bf(v);
      }
    }
  }
}
#undef STAGE_TILE
#undef COMPUTE_TILE

// ---------- 8. combine: out = g0*h2[s0] + g1*h2[s1] ----------
__global__ __launch_bounds__(256) void combine_kernel(
    const u16* __restrict__ h2, const int* __restrict__ slot,
    const float* __restrict__ gat, float* __restrict__ out) {
  int i = blockIdx.x * 256 + threadIdx.x;  // over N*512/8
  int t = i >> 6;
  int c = (i & 63) * 8;
  int s0 = slot[t * 2], s1 = slot[t * 2 + 1];
  float g0 = gat[t * 2], g1 = gat[t * 2 + 1];
  bf16x8 a = *(const bf16x8*)&h2[(size_t)s0 * DIMD + c];
  bf16x8 b = *(const bf16x8*)&h2[(size_t)s1 * DIMD + c];
  float4 o0, o1;
  o0.x = g0 * bf2f(a[0]) + g1 * bf2f(b[0]);
  o0.y = g0 * bf2f(a[1]) + g1 * bf2f(b[1]);
  o0.z = g0 * bf2f(a[2]) + g1 * bf2f(b[2]);
  o0.w = g0 * bf2f(a[3]) + g1 * bf2f(b[3]);
  o1.x = g0 * bf2f(a[4]) + g1 * bf2f(b[4]);
  o1.y = g0 * bf2f(a[5]) + g1 * bf2f(b[5]);
  o1.z = g0 * bf2f(a[6]) + g1 * bf2f(b[6]);
  o1.w = g0 * bf2f(a[7]) + g1 * bf2f(b[7]);
  float* op = out + (size_t)t * DIMD + c;
  *(float4*)op = o0;
  *(float4*)(op + 4) = o1;
}

extern "C" void kernel_launch(void* const* d_in, const int* in_sizes, int n_in,
                              void* d_out, int out_size, void* d_ws, size_t ws_size,
                              hipStream_t stream) {
  const float* x  = (const float*)d_in[0];
  const float* Wr = (const float*)d_in[1];
  const float* W1 = (const float*)d_in[2];
  const float* W2 = (const float*)d_in[3];
  float* out = (float*)d_out;
  char* ws = (char*)d_ws;

  // workspace layout — total 204,481,024 B (known to fit)
  u16*   xb   = (u16*)(ws);                      // 33,554,432
  u16*   W1b  = (u16*)(ws + 33554432ull);        // 16,777,216
  u16*   W2b  = (u16*)(ws + 50331648ull);        // 16,777,216
  int*   eidx = (int*)(ws + 67108864ull);        // 262,144
  float* gat  = (float*)(ws + 67371008ull);      // 262,144
  int*   slot = (int*)(ws + 67633152ull);        // 262,144
  int*   perm = (int*)(ws + 67895296ull);        // 266,240
  int*   meta = (int*)(ws + 68161536ull);        // 4,608
  u16*   h2   = (u16*)(ws + 68166144ull);        // 68,157,440 (PADMAX*512*2)
  u16*   hc   = (u16*)(ws + 136323584ull);       // 68,157,440 (TPC*128*2048*2)

  if (ws_size < 204481024ull) {
    fprintf(stderr, "[moe kernel] ws_size=%zu too small (need 204481024)\n", ws_size);
    return;
  }

  init_kernel<<<1, 64, 0, stream>>>(meta);
  router_kernel<<<NTOK / 4, 256, 0, stream>>>(x, Wr, xb, eidx, gat);
  count_kernel<<<(NTOK * 2) / 256, 256, 0, stream>>>(eidx, meta);
  scan_kernel<<<1, 256, 0, stream>>>(meta, perm);
  scatter_kernel<<<(NTOK * 2) / 256, 256, 0, stream>>>(eidx, meta, perm, slot);

  cvt_kernel<<<(NEXP * FFD * DIMD) / 1024, 256, 0, stream>>>(W1, W1b);
  cvt_kernel<<<(NEXP * DIMD * FFD) / 1024, 256, 0, stream>>>(W2, W2b);

  for (int c = 0; c < NCHUNK; ++c) {
    int t0 = c * TPC;
    // GEMM1: hc[slot-t0*128][0:2048] = gelu( xb[perm[slot]] @ W1[e]^T ), K=512
    // 1-D XCD-chunked, panel-fastest: A-tile stays L2-resident per XCD
    gemm_kernel<128, 1><<<TPC * (FFD / 128), 512, 0, stream>>>(
        xb, DIMD, perm, 0,
        W1b, DIMD, (size_t)FFD * DIMD,
        hc, FFD, t0 * BM, 1, DIMD, t0, FFD / 128, TPC, meta);
    // GEMM2: h2[slot][0:512] = hc[slot-t0*128] @ W2[e]^T, K=2048 (64-row units)
    gemm_kernel<64, 1><<<TPC * 2 * (DIMD / 128), 512, 0, stream>>>(
        hc, FFD, nullptr, t0 * BM,
        W2b, FFD, (size_t)DIMD * FFD,
        h2, DIMD, 0, 0, FFD, t0, DIMD / 128, TPC * 2, meta);
  }

  combine_kernel<<<(NTOK * DIMD) / 8 / 256, 256, 0, stream>>>(h2, slot, gat, out);
}